// Round 9
// baseline (867.035 us; speedup 1.0000x reference)
//
#include <hip/hip_runtime.h>
#include <hip/hip_cooperative_groups.h>

namespace cg = cooperative_groups;

#define BN_EPS 1e-5f

using f4 = __attribute__((ext_vector_type(4))) float;
using h4 = __attribute__((ext_vector_type(4))) _Float16;

__device__ inline f4 relu4(f4 v) {
    v.x = fmaxf(v.x, 0.f); v.y = fmaxf(v.y, 0.f);
    v.z = fmaxf(v.z, 0.f); v.w = fmaxf(v.w, 0.f);
    return v;
}

struct MegaParams {
    const float* x; const int* ei; const float* ea;
    const float* W1; const float* b1; const float* gamma; const float* beta;
    const float* W2; const float* b2;
    float* out; float* buf; float* sums; _Float16* eah;
    int* canon; int* deg; int* rowptr; int* cursor; int2* pbuf;
    int* partials; int* flag;
    int N, E, L, npairs;
};

// ===========================================================================
// Device phase functions (shared by mega kernel and fallback kernels)
// ===========================================================================
__device__ inline void dev_init(int* deg, float* sums, int* flag,
                                int N, int nsum, int gsize, int gtid) {
    for (int i = gtid; i < N; i += gsize) deg[i] = 0;
    for (int i = gtid; i < nsum; i += gsize) sums[i] = 0.f;
    if (gtid == 0) *flag = 1;
}

__device__ inline void dev_detect(const int* ei, int* flag, int npairs,
                                  int gsize, int gtid) {
    bool bad = false;
    for (int i = gtid; i < npairs; i += gsize) bad |= (ei[2 * i + 1] != 0);
    if (bad) atomicAnd(flag, 0);
}

__device__ inline void dev_canon(const int* ei, const int* flag, int* canon,
                                 int* deg, int n2, int E, int gsize, int gtid) {
    int wide = *flag;
    for (int i = gtid; i < n2; i += gsize) {
        int v = wide ? ei[2 * i] : ei[i];
        canon[i] = v;
        if (i >= E) atomicAdd(deg + v, 1);
    }
}

// block-cooperative local scan over 1024-element chunks (grid-stride chunks)
__device__ inline void dev_scan_local(const int* deg, int* rowptr, int* partials,
                                      int N, int* sInt) {
    int t = threadIdx.x;
    int nchunks = (N + 1023) >> 10;
    for (int c = blockIdx.x; c < (int)nchunks; c += gridDim.x) {
        int base = (c << 10) + t * 4;
        int4 v = make_int4(0, 0, 0, 0);
        if (base + 3 < N) v = *(const int4*)(deg + base);
        else {
            if (base < N) v.x = deg[base];
            if (base + 1 < N) v.y = deg[base + 1];
            if (base + 2 < N) v.z = deg[base + 2];
            if (base + 3 < N) v.w = deg[base + 3];
        }
        int s = v.x + v.y + v.z + v.w;
        __syncthreads();              // protect sInt reuse across chunks
        sInt[t] = s;
        __syncthreads();
        for (int off = 1; off < 256; off <<= 1) {
            int u = (t >= off) ? sInt[t - off] : 0;
            __syncthreads();
            sInt[t] += u;
            __syncthreads();
        }
        int excl = (t == 0) ? 0 : sInt[t - 1];
        int4 w;
        w.x = excl;
        w.y = excl + v.x;
        w.z = w.y + v.y;
        w.w = w.z + v.z;
        if (base + 3 < N) *(int4*)(rowptr + base) = w;
        else {
            if (base < N) rowptr[base] = w.x;
            if (base + 1 < N) rowptr[base + 1] = w.y;
            if (base + 2 < N) rowptr[base + 2] = w.z;
            if (base + 3 < N) rowptr[base + 3] = w.w;
        }
        if (t == 255) partials[c] = sInt[255];
    }
}

__device__ inline void dev_scan_add(int* rowptr, int* cursor, const int* partials,
                                    int N, int E, int* sOff, int gsize, int gtid) {
    int nchunks = (N + 1023) >> 10;
    if (threadIdx.x == 0) {
        int run = 0;
        for (int c = 0; c < nchunks; ++c) { sOff[c] = run; run += partials[c]; }
    }
    __syncthreads();
    for (int i = gtid; i < N; i += gsize) {
        int v = rowptr[i] + sOff[i >> 10];
        rowptr[i] = v;
        cursor[i] = v;
    }
    if (gtid == 0) rowptr[N] = E;
}

__device__ inline void dev_fill(const int* src, const int* dst, int* cursor,
                                int2* pbuf, int E, int gsize, int gtid) {
    for (int e = gtid; e < E; e += gsize) {
        int d = dst[e];
        int pos = atomicAdd(cursor + d, 1);
        pbuf[pos] = make_int2(e, src[e]);
    }
}

// gather: one node per 32-lane group, grid-stride over nodes.
// mode 0: ea fp32 random NT read + sequential fp16 eah write
// mode 1: eah fp16 sequential read
// mode 2: ea fp32 random NT read only
__device__ inline void dev_gather(const float* x, const float* ea, _Float16* eah,
                                  const int* rowptr, const int2* pbuf,
                                  float* aggx, int N, int mode,
                                  int gid, int ngroups, int f) {
    for (int n = gid; n < N; n += ngroups) {
        int lo = rowptr[n], hi = rowptr[n + 1];
        f4 acc0 = ((const f4*)(x + (size_t)n * 128))[f];  // self row (eps=0)
        f4 acc1 = {0.f, 0.f, 0.f, 0.f};
        f4 acc2 = {0.f, 0.f, 0.f, 0.f};
        f4 acc3 = {0.f, 0.f, 0.f, 0.f};
        int i = lo;
        if (mode == 1) {
            const h4* ep = (const h4*)eah;
            for (; i + 4 <= hi; i += 4) {
                int2 q0 = pbuf[i];
                int2 q1 = pbuf[i + 1];
                int2 q2 = pbuf[i + 2];
                int2 q3 = pbuf[i + 3];
                f4 xa = ((const f4*)(x + (size_t)q0.y * 128))[f];
                h4 ha = ep[(size_t)i * 32 + f];
                f4 xb = ((const f4*)(x + (size_t)q1.y * 128))[f];
                h4 hb = ep[(size_t)(i + 1) * 32 + f];
                f4 xc = ((const f4*)(x + (size_t)q2.y * 128))[f];
                h4 hc = ep[(size_t)(i + 2) * 32 + f];
                f4 xd = ((const f4*)(x + (size_t)q3.y * 128))[f];
                h4 hd = ep[(size_t)(i + 3) * 32 + f];
                acc0 += relu4(xa + __builtin_convertvector(ha, f4));
                acc1 += relu4(xb + __builtin_convertvector(hb, f4));
                acc2 += relu4(xc + __builtin_convertvector(hc, f4));
                acc3 += relu4(xd + __builtin_convertvector(hd, f4));
            }
            for (; i < hi; ++i) {
                int2 q0 = pbuf[i];
                f4 xa = ((const f4*)(x + (size_t)q0.y * 128))[f];
                h4 ha = ep[(size_t)i * 32 + f];
                acc0 += relu4(xa + __builtin_convertvector(ha, f4));
            }
        } else {
            h4* ep = (h4*)eah;
            for (; i + 4 <= hi; i += 4) {
                int2 q0 = pbuf[i];
                int2 q1 = pbuf[i + 1];
                int2 q2 = pbuf[i + 2];
                int2 q3 = pbuf[i + 3];
                f4 xa = ((const f4*)(x + (size_t)q0.y * 128))[f];
                f4 aa = __builtin_nontemporal_load(((const f4*)(ea + (size_t)q0.x * 128)) + f);
                f4 xb = ((const f4*)(x + (size_t)q1.y * 128))[f];
                f4 ab = __builtin_nontemporal_load(((const f4*)(ea + (size_t)q1.x * 128)) + f);
                f4 xc = ((const f4*)(x + (size_t)q2.y * 128))[f];
                f4 ac = __builtin_nontemporal_load(((const f4*)(ea + (size_t)q2.x * 128)) + f);
                f4 xd = ((const f4*)(x + (size_t)q3.y * 128))[f];
                f4 ad = __builtin_nontemporal_load(((const f4*)(ea + (size_t)q3.x * 128)) + f);
                if (mode == 0) {
                    ep[(size_t)i * 32 + f] = __builtin_convertvector(aa, h4);  // sequential
                    ep[(size_t)(i + 1) * 32 + f] = __builtin_convertvector(ab, h4);
                    ep[(size_t)(i + 2) * 32 + f] = __builtin_convertvector(ac, h4);
                    ep[(size_t)(i + 3) * 32 + f] = __builtin_convertvector(ad, h4);
                }
                acc0 += relu4(xa + aa);
                acc1 += relu4(xb + ab);
                acc2 += relu4(xc + ac);
                acc3 += relu4(xd + ad);
            }
            for (; i < hi; ++i) {
                int2 q0 = pbuf[i];
                f4 xa = ((const f4*)(x + (size_t)q0.y * 128))[f];
                f4 aa = __builtin_nontemporal_load(((const f4*)(ea + (size_t)q0.x * 128)) + f);
                if (mode == 0) ep[(size_t)i * 32 + f] = __builtin_convertvector(aa, h4);
                acc0 += relu4(xa + aa);
            }
        }
        f4 r = (acc0 + acc1) + (acc2 + acc3);
        ((f4*)(aggx + (size_t)n * 128))[f] = r;
    }
}

// GEMM1 (in-place capable), 32-row tiles, grid-stride; fused BN stats.
__device__ inline void dev_gemm1(const float* A, const float* W, const float* bias,
                                 float* sums, float* out, int N,
                                 float (*sA)[132], float (*sW)[128]) {
    int t = threadIdx.x;
    int cgc = t & 15, rg = t >> 4;
    int c0a = cgc * 4;
    int c0b = 64 + cgc * 4;
    float4 b0 = *reinterpret_cast<const float4*>(bias + c0a);
    float4 b1v = *reinterpret_cast<const float4*>(bias + c0b);
    float cs[8], cs2[8];
#pragma unroll
    for (int j = 0; j < 8; ++j) { cs[j] = 0.f; cs2[j] = 0.f; }

    int ntiles = (N + 31) >> 5;
    for (int tb = blockIdx.x; tb < ntiles; tb += gridDim.x) {
        int rbase = tb << 5;
        __syncthreads();  // protect sA/sW reuse from previous tile
        {
            int colq = t & 31;
            int r0 = t >> 5;
#pragma unroll
            for (int it = 0; it < 4; ++it) {
                int r = r0 + it * 8;
                int row = rbase + r;
                float4 v = make_float4(0.f, 0.f, 0.f, 0.f);
                if (row < N) v = reinterpret_cast<const float4*>(A + (size_t)row * 128)[colq];
                *reinterpret_cast<float4*>(&sA[r][colq * 4]) = v;
            }
        }
        float acc[2][8];
#pragma unroll
        for (int r = 0; r < 2; ++r)
#pragma unroll
            for (int c = 0; c < 8; ++c) acc[r][c] = 0.f;

        for (int kc = 0; kc < 4; ++kc) {
            __syncthreads();
#pragma unroll
            for (int pass = 0; pass < 4; ++pass) {
                int kk = (t >> 5) + pass * 8;
                int k = kc * 32 + kk;
                float4 w = reinterpret_cast<const float4*>(W + (size_t)k * 128)[t & 31];
                *reinterpret_cast<float4*>(&sW[kk][(t & 31) * 4]) = w;
            }
            __syncthreads();
#pragma unroll
            for (int kk0 = 0; kk0 < 32; kk0 += 4) {
                float4 a[2];
#pragma unroll
                for (int r = 0; r < 2; ++r)
                    a[r] = *reinterpret_cast<const float4*>(&sA[rg * 2 + r][kc * 32 + kk0]);
#pragma unroll
                for (int j = 0; j < 4; ++j) {
                    float4 w0 = *reinterpret_cast<const float4*>(&sW[kk0 + j][c0a]);
                    float4 w1 = *reinterpret_cast<const float4*>(&sW[kk0 + j][c0b]);
#pragma unroll
                    for (int r = 0; r < 2; ++r) {
                        float av = (j == 0) ? a[r].x : (j == 1) ? a[r].y : (j == 2) ? a[r].z : a[r].w;
                        acc[r][0] += av * w0.x;
                        acc[r][1] += av * w0.y;
                        acc[r][2] += av * w0.z;
                        acc[r][3] += av * w0.w;
                        acc[r][4] += av * w1.x;
                        acc[r][5] += av * w1.y;
                        acc[r][6] += av * w1.z;
                        acc[r][7] += av * w1.w;
                    }
                }
            }
        }
#pragma unroll
        for (int r = 0; r < 2; ++r) {
            int row = rbase + rg * 2 + r;
            if (row >= N) continue;
            float4 o0, o1;
            o0.x = acc[r][0] + b0.x;  o0.y = acc[r][1] + b0.y;
            o0.z = acc[r][2] + b0.z;  o0.w = acc[r][3] + b0.w;
            o1.x = acc[r][4] + b1v.x; o1.y = acc[r][5] + b1v.y;
            o1.z = acc[r][6] + b1v.z; o1.w = acc[r][7] + b1v.w;
            cs[0] += o0.x; cs2[0] += o0.x * o0.x;
            cs[1] += o0.y; cs2[1] += o0.y * o0.y;
            cs[2] += o0.z; cs2[2] += o0.z * o0.z;
            cs[3] += o0.w; cs2[3] += o0.w * o0.w;
            cs[4] += o1.x; cs2[4] += o1.x * o1.x;
            cs[5] += o1.y; cs2[5] += o1.y * o1.y;
            cs[6] += o1.z; cs2[6] += o1.z * o1.z;
            cs[7] += o1.w; cs2[7] += o1.w * o1.w;
            *reinterpret_cast<float4*>(out + (size_t)row * 128 + c0a) = o0;
            *reinterpret_cast<float4*>(out + (size_t)row * 128 + c0b) = o1;
        }
    }

    // block reduction of cs/cs2 via sA scratch, then 1 atomic/col
    __syncthreads();
    float* red = &sA[0][0];
    float* red2 = red + 2048;
    int base = t * 8;
#pragma unroll
    for (int j = 0; j < 8; ++j) { red[base + j] = cs[j]; red2[base + j] = cs2[j]; }
    __syncthreads();
    if (t < 128) {
        int cgj = (t & 63) >> 2;
        int j = (t & 3) + ((t >> 6) << 2);
        float s = 0.f, s2 = 0.f;
#pragma unroll
        for (int rr = 0; rr < 16; ++rr) {
            s += red[(rr * 16 + cgj) * 8 + j];
            s2 += red2[(rr * 16 + cgj) * 8 + j];
        }
        unsafeAtomicAdd(&sums[t], s);
        unsafeAtomicAdd(&sums[128 + t], s2);
    }
    __syncthreads();
}

// GEMM2: out = relu( relu(h*scale + shift) @ W2 + b2 ), 32-row tiles.
__device__ inline void dev_gemm2(const float* A, const float* W, const float* bias,
                                 const float* sums, const float* gamma,
                                 const float* beta, float* out, int N, float invN,
                                 float (*sA)[132], float (*sW)[128],
                                 float* sScale, float* sShift) {
    int t = threadIdx.x;
    __syncthreads();
    if (t < 128) {
        float mean = sums[t] * invN;
        float var = sums[128 + t] * invN - mean * mean;
        float inv = rsqrtf(var + BN_EPS);
        float sc = gamma[t] * inv;
        sScale[t] = sc;
        sShift[t] = beta[t] - mean * sc;
    }
    __syncthreads();

    int cgc = t & 15, rg = t >> 4;
    int c0a = cgc * 4;
    int c0b = 64 + cgc * 4;
    float4 b0 = *reinterpret_cast<const float4*>(bias + c0a);
    float4 b1v = *reinterpret_cast<const float4*>(bias + c0b);

    int ntiles = (N + 31) >> 5;
    for (int tb = blockIdx.x; tb < ntiles; tb += gridDim.x) {
        int rbase = tb << 5;
        __syncthreads();
        {
            int colq = t & 31;
            int r0 = t >> 5;
            float4 s4 = reinterpret_cast<const float4*>(sScale)[colq];
            float4 sh4 = reinterpret_cast<const float4*>(sShift)[colq];
#pragma unroll
            for (int it = 0; it < 4; ++it) {
                int r = r0 + it * 8;
                int row = rbase + r;
                float4 v = make_float4(0.f, 0.f, 0.f, 0.f);
                if (row < N) {
                    float4 a = reinterpret_cast<const float4*>(A + (size_t)row * 128)[colq];
                    v.x = fmaxf(a.x * s4.x + sh4.x, 0.f);
                    v.y = fmaxf(a.y * s4.y + sh4.y, 0.f);
                    v.z = fmaxf(a.z * s4.z + sh4.z, 0.f);
                    v.w = fmaxf(a.w * s4.w + sh4.w, 0.f);
                }
                *reinterpret_cast<float4*>(&sA[r][colq * 4]) = v;
            }
        }
        float acc[2][8];
#pragma unroll
        for (int r = 0; r < 2; ++r)
#pragma unroll
            for (int c = 0; c < 8; ++c) acc[r][c] = 0.f;

        for (int kc = 0; kc < 4; ++kc) {
            __syncthreads();
#pragma unroll
            for (int pass = 0; pass < 4; ++pass) {
                int kk = (t >> 5) + pass * 8;
                int k = kc * 32 + kk;
                float4 w = reinterpret_cast<const float4*>(W + (size_t)k * 128)[t & 31];
                *reinterpret_cast<float4*>(&sW[kk][(t & 31) * 4]) = w;
            }
            __syncthreads();
#pragma unroll
            for (int kk0 = 0; kk0 < 32; kk0 += 4) {
                float4 a[2];
#pragma unroll
                for (int r = 0; r < 2; ++r)
                    a[r] = *reinterpret_cast<const float4*>(&sA[rg * 2 + r][kc * 32 + kk0]);
#pragma unroll
                for (int j = 0; j < 4; ++j) {
                    float4 w0 = *reinterpret_cast<const float4*>(&sW[kk0 + j][c0a]);
                    float4 w1 = *reinterpret_cast<const float4*>(&sW[kk0 + j][c0b]);
#pragma unroll
                    for (int r = 0; r < 2; ++r) {
                        float av = (j == 0) ? a[r].x : (j == 1) ? a[r].y : (j == 2) ? a[r].z : a[r].w;
                        acc[r][0] += av * w0.x;
                        acc[r][1] += av * w0.y;
                        acc[r][2] += av * w0.z;
                        acc[r][3] += av * w0.w;
                        acc[r][4] += av * w1.x;
                        acc[r][5] += av * w1.y;
                        acc[r][6] += av * w1.z;
                        acc[r][7] += av * w1.w;
                    }
                }
            }
        }
#pragma unroll
        for (int r = 0; r < 2; ++r) {
            int row = rbase + rg * 2 + r;
            if (row >= N) continue;
            float4 o0, o1;
            o0.x = fmaxf(acc[r][0] + b0.x, 0.f);  o0.y = fmaxf(acc[r][1] + b0.y, 0.f);
            o0.z = fmaxf(acc[r][2] + b0.z, 0.f);  o0.w = fmaxf(acc[r][3] + b0.w, 0.f);
            o1.x = fmaxf(acc[r][4] + b1v.x, 0.f); o1.y = fmaxf(acc[r][5] + b1v.y, 0.f);
            o1.z = fmaxf(acc[r][6] + b1v.z, 0.f); o1.w = fmaxf(acc[r][7] + b1v.w, 0.f);
            *reinterpret_cast<float4*>(out + (size_t)row * 128 + c0a) = o0;
            *reinterpret_cast<float4*>(out + (size_t)row * 128 + c0b) = o1;
        }
    }
    __syncthreads();
}

// ===========================================================================
// The mega kernel: the whole pipeline in one cooperative dispatch.
// ===========================================================================
__global__ __launch_bounds__(256, 4) void mega_kernel(MegaParams p) {
    cg::grid_group grid = cg::this_grid();
    __shared__ float sA[32][132];
    __shared__ float sW[32][128];
    __shared__ float sScale[128];
    __shared__ float sShift[128];
    __shared__ int sOff[128];

    int t = threadIdx.x;
    int gtid = blockIdx.x * 256 + t;
    int gsize = gridDim.x * 256;

    dev_init(p.deg, p.sums, p.flag, p.N, 256 * p.L, gsize, gtid);
    grid.sync();
    dev_detect(p.ei, p.flag, p.npairs, gsize, gtid);
    grid.sync();
    dev_canon(p.ei, p.flag, p.canon, p.deg, 2 * p.E, p.E, gsize, gtid);
    grid.sync();
    dev_scan_local(p.deg, p.rowptr, p.partials, p.N, (int*)&sA[0][0]);
    grid.sync();
    dev_scan_add(p.rowptr, p.cursor, p.partials, p.N, p.E, sOff, gsize, gtid);
    grid.sync();
    dev_fill(p.canon, p.canon + p.E, p.cursor, p.pbuf, p.E, gsize, gtid);
    grid.sync();

    int gid = gtid >> 5;
    int ngroups = gsize >> 5;
    int f = t & 31;
    float invN = 1.0f / (float)p.N;
    const float* xin = p.x;
    for (int l = 0; l < p.L; ++l) {
        int mode = (l == 0) ? ((p.L > 1) ? 0 : 2) : 1;
        dev_gather(xin, p.ea, p.eah, p.rowptr, p.pbuf, p.buf, p.N, mode, gid, ngroups, f);
        grid.sync();
        dev_gemm1(p.buf, p.W1 + (size_t)l * 16384, p.b1 + (size_t)l * 128,
                  p.sums + (size_t)l * 256, p.buf, p.N, sA, sW);
        grid.sync();
        dev_gemm2(p.buf, p.W2 + (size_t)l * 16384, p.b2 + (size_t)l * 128,
                  p.sums + (size_t)l * 256, p.gamma + (size_t)l * 128,
                  p.beta + (size_t)l * 128, p.out, p.N, invN, sA, sW, sScale, sShift);
        grid.sync();
        xin = p.out;
    }
}

// ===========================================================================
// Fallback kernels (non-cooperative path, proven R8 structure)
// ===========================================================================
__global__ __launch_bounds__(256) void fb_init_kernel(int* deg, float* sums, int* flag,
                                                      int N, int nsum) {
    int gtid = blockIdx.x * 256 + threadIdx.x;
    int gsize = gridDim.x * 256;
    dev_init(deg, sums, flag, N, nsum, gsize, gtid);
}
__global__ __launch_bounds__(256) void fb_detect_kernel(const int* ei, int* flag, int npairs) {
    dev_detect(ei, flag, npairs, gridDim.x * 256, blockIdx.x * 256 + threadIdx.x);
}
__global__ __launch_bounds__(256) void fb_canon_kernel(const int* ei, const int* flag,
                                                       int* canon, int* deg, int n2, int E) {
    dev_canon(ei, flag, canon, deg, n2, E, gridDim.x * 256, blockIdx.x * 256 + threadIdx.x);
}
__global__ __launch_bounds__(256) void fb_scan_local_kernel(const int* deg, int* rowptr,
                                                            int* partials, int N) {
    __shared__ int sInt[256];
    dev_scan_local(deg, rowptr, partials, N, sInt);
}
__global__ __launch_bounds__(256) void fb_scan_add_kernel(int* rowptr, int* cursor,
                                                          const int* partials, int N, int E) {
    __shared__ int sOff[128];
    dev_scan_add(rowptr, cursor, partials, N, E, sOff,
                 gridDim.x * 256, blockIdx.x * 256 + threadIdx.x);
}
__global__ __launch_bounds__(256) void fb_fill_kernel(const int* src, const int* dst,
                                                      int* cursor, int2* pbuf, int E) {
    dev_fill(src, dst, cursor, pbuf, E, gridDim.x * 256, blockIdx.x * 256 + threadIdx.x);
}
__global__ __launch_bounds__(256) void fb_gather_kernel(const float* x, const float* ea,
                                                        _Float16* eah, const int* rowptr,
                                                        const int2* pbuf, float* aggx,
                                                        int N, int mode) {
    int gtid = blockIdx.x * 256 + threadIdx.x;
    dev_gather(x, ea, eah, rowptr, pbuf, aggx, N, mode,
               gtid >> 5, (gridDim.x * 256) >> 5, threadIdx.x & 31);
}
__global__ __launch_bounds__(256) void fb_gemm1_kernel(const float* A, const float* W,
                                                       const float* bias, float* sums,
                                                       float* out, int N) {
    __shared__ float sA[32][132];
    __shared__ float sW[32][128];
    dev_gemm1(A, W, bias, sums, out, N, sA, sW);
}
__global__ __launch_bounds__(256) void fb_gemm2_kernel(const float* A, const float* W,
                                                       const float* bias, const float* sums,
                                                       const float* gamma, const float* beta,
                                                       float* out, int N, float invN) {
    __shared__ float sA[32][132];
    __shared__ float sW[32][128];
    __shared__ float sScale[128];
    __shared__ float sShift[128];
    dev_gemm2(A, W, bias, sums, gamma, beta, out, N, invN, sA, sW, sScale, sShift);
}

// ===========================================================================
extern "C" void kernel_launch(void* const* d_in, const int* in_sizes, int n_in,
                              void* d_out, int out_size, void* d_ws, size_t ws_size,
                              hipStream_t stream) {
    const float* x     = (const float*)d_in[0];
    const int*   ei    = (const int*)d_in[1];
    const float* ea    = (const float*)d_in[2];
    const float* W1    = (const float*)d_in[3];
    const float* b1    = (const float*)d_in[4];
    const float* gamma = (const float*)d_in[5];
    const float* beta  = (const float*)d_in[6];
    const float* W2    = (const float*)d_in[7];
    const float* b2    = (const float*)d_in[8];

    int N = in_sizes[0] / 128;
    int E = in_sizes[2] / 128;
    int L = in_sizes[3] / (128 * 128);

    size_t NF = (size_t)N * 128;
    float*     buf    = (float*)d_ws;                  // gather out + gemm1 in-place
    float*     sums   = buf + NF;                      // 256*L floats
    _Float16*  eah    = (_Float16*)(sums + 256 * L);   // E*128 halves (bucket order)
    int*       canon  = (int*)(eah + (size_t)E * 128);
    int*       deg    = canon + (size_t)2 * E;
    int*       rowptr = deg + N;
    int*       cursor = rowptr + N + 2;                // pad keeps pbuf 8B-aligned
    int2*      pbuf   = (int2*)(cursor + N);           // (edge id, src id), bucket order
    int*       partials = (int*)(pbuf + E);
    int*       flag   = partials + ((N + 1023) / 1024) + 1;

    int npairs = (E < 4096) ? E : 4096;

    // ---- Cooperative grid sizing (cached) ----
    static int coopBlocks = -1;
    if (coopBlocks < 0) {
        int nb = 0;
        hipError_t e1 = hipOccupancyMaxActiveBlocksPerMultiprocessor(&nb, mega_kernel, 256, 0);
        hipDeviceProp_t prop{};
        hipError_t e2 = hipGetDeviceProperties(&prop, 0);
        if (e1 == hipSuccess && e2 == hipSuccess && nb > 0 && prop.multiProcessorCount > 0)
            coopBlocks = nb * prop.multiProcessorCount;
        else
            coopBlocks = 0;
        if (coopBlocks > 4096) coopBlocks = 4096;
    }

    bool launched = false;
    if (coopBlocks > 0) {
        MegaParams p;
        p.x = x; p.ei = ei; p.ea = ea;
        p.W1 = W1; p.b1 = b1; p.gamma = gamma; p.beta = beta;
        p.W2 = W2; p.b2 = b2;
        p.out = (float*)d_out; p.buf = buf; p.sums = sums; p.eah = eah;
        p.canon = canon; p.deg = deg; p.rowptr = rowptr; p.cursor = cursor;
        p.pbuf = pbuf; p.partials = partials; p.flag = flag;
        p.N = N; p.E = E; p.L = L; p.npairs = npairs;
        void* args[] = { (void*)&p };
        hipError_t rc = hipLaunchCooperativeKernel((const void*)mega_kernel,
                                                   dim3(coopBlocks), dim3(256),
                                                   args, 0, stream);
        launched = (rc == hipSuccess);
    }

    if (!launched) {
        // -------- non-cooperative fallback (R8-equivalent sequence) --------
        int gridS = 2048;
        fb_init_kernel<<<(N + 255) / 256, 256, 0, stream>>>(deg, sums, flag, N, 256 * L);
        fb_detect_kernel<<<1, 256, 0, stream>>>(ei, flag, npairs);
        int E2 = 2 * E;
        fb_canon_kernel<<<(E2 + 255) / 256, 256, 0, stream>>>(ei, flag, canon, deg, E2, E);
        int nb2 = (N + 1023) / 1024;
        fb_scan_local_kernel<<<nb2, 256, 0, stream>>>(deg, rowptr, partials, N);
        fb_scan_add_kernel<<<(N + 256) / 256, 256, 0, stream>>>(rowptr, cursor, partials, N, E);
        fb_fill_kernel<<<(E + 255) / 256, 256, 0, stream>>>(canon, canon + E, cursor, pbuf, E);
        int gatherBlocks = (N * 32 + 255) / 256;
        int gemmBlocks = (N + 31) / 32;
        if (gemmBlocks > gridS) gemmBlocks = gridS;
        float invN = 1.0f / (float)N;
        const float* xin = x;
        for (int l = 0; l < L; ++l) {
            float* xout = (float*)d_out;
            float* sums_l = sums + (size_t)l * 256;
            int mode = (l == 0) ? ((L > 1) ? 0 : 2) : 1;
            fb_gather_kernel<<<gatherBlocks, 256, 0, stream>>>(xin, ea, eah, rowptr,
                                                               pbuf, buf, N, mode);
            fb_gemm1_kernel<<<gemmBlocks, 256, 0, stream>>>(buf, W1 + (size_t)l * 16384,
                                                            b1 + (size_t)l * 128, sums_l,
                                                            buf, N);
            fb_gemm2_kernel<<<gemmBlocks, 256, 0, stream>>>(buf, W2 + (size_t)l * 16384,
                                                            b2 + (size_t)l * 128, sums_l,
                                                            gamma + (size_t)l * 128,
                                                            beta + (size_t)l * 128,
                                                            xout, N, invN);
            xin = xout;
        }
    }
}

// Round 12
// 654.782 us; speedup vs baseline: 1.3242x; 1.3242x over previous
//
#include <hip/hip_runtime.h>

#define BN_EPS 1e-5f

using f4 = __attribute__((ext_vector_type(4))) float;
using h4 = __attribute__((ext_vector_type(4))) _Float16;

__device__ inline f4 relu4(f4 v) {
    v.x = fmaxf(v.x, 0.f); v.y = fmaxf(v.y, 0.f);
    v.z = fmaxf(v.z, 0.f); v.w = fmaxf(v.w, 0.f);
    return v;
}

// ---------------------------------------------------------------------------
// detect int64-vs-int32 edge marshalling; also zeroes deg[N]
// ---------------------------------------------------------------------------
__global__ __launch_bounds__(256) void detect_i64_kernel(const int* __restrict__ ei,
                                                         int* __restrict__ flag, int npairs,
                                                         int* __restrict__ deg, int N) {
    __shared__ int ok;
    if (threadIdx.x == 0) ok = 1;
    __syncthreads();
    bool bad = false;
    for (int i = threadIdx.x; i < npairs; i += 256)
        bad |= (ei[2 * i + 1] != 0);
    if (bad) ok = 0;
    int nq = N >> 2;
    int4* d4 = (int4*)deg;
    for (int i = threadIdx.x; i < nq; i += 256) d4[i] = make_int4(0, 0, 0, 0);
    for (int i = (nq << 2) + threadIdx.x; i < N; i += 256) deg[i] = 0;
    __syncthreads();
    if (threadIdx.x == 0) *flag = ok;
}

// canon + fused degree histogram (dst entries live in canon[E..2E))
__global__ __launch_bounds__(256) void canon_kernel(const int* __restrict__ ei,
                                                    const int* __restrict__ flag,
                                                    int* __restrict__ canon,
                                                    int* __restrict__ deg, int n2, int E) {
    int i = blockIdx.x * 256 + threadIdx.x;
    if (i >= n2) return;
    int wide = *flag;
    int v = wide ? ei[2 * i] : ei[i];
    canon[i] = v;
    if (i >= E) atomicAdd(&deg[v], 1);
}

// ---------------------------------------------------------------------------
// 3-stage parallel exclusive scan: deg[N] -> rowptr[N+1], cursor[N]
// ---------------------------------------------------------------------------
__global__ __launch_bounds__(256) void scan_blk_kernel(const int* __restrict__ deg,
                                                       int* __restrict__ rowptr,
                                                       int* __restrict__ partials, int N) {
    __shared__ int s[256];
    int b = blockIdx.x, t = threadIdx.x;
    int base = b * 1024 + t * 4;
    int4 v = make_int4(0, 0, 0, 0);
    if (base + 3 < N) v = *(const int4*)(deg + base);
    else {
        if (base < N) v.x = deg[base];
        if (base + 1 < N) v.y = deg[base + 1];
        if (base + 2 < N) v.z = deg[base + 2];
        if (base + 3 < N) v.w = deg[base + 3];
    }
    s[t] = v.x + v.y + v.z + v.w;
    __syncthreads();
    for (int off = 1; off < 256; off <<= 1) {
        int u = (t >= off) ? s[t - off] : 0;
        __syncthreads();
        s[t] += u;
        __syncthreads();
    }
    int excl = (t == 0) ? 0 : s[t - 1];
    int4 w;
    w.x = excl;
    w.y = excl + v.x;
    w.z = w.y + v.y;
    w.w = w.z + v.z;
    if (base + 3 < N) *(int4*)(rowptr + base) = w;
    else {
        if (base < N) rowptr[base] = w.x;
        if (base + 1 < N) rowptr[base + 1] = w.y;
        if (base + 2 < N) rowptr[base + 2] = w.z;
        if (base + 3 < N) rowptr[base + 3] = w.w;
    }
    if (t == 255) partials[b] = s[255];
}

__global__ __launch_bounds__(256) void scan_part_kernel(int* __restrict__ partials, int nb) {
    __shared__ int s[256];
    int t = threadIdx.x;
    if (nb <= 256) {
        s[t] = (t < nb) ? partials[t] : 0;
        __syncthreads();
        for (int off = 1; off < 256; off <<= 1) {
            int u = (t >= off) ? s[t - off] : 0;
            __syncthreads();
            s[t] += u;
            __syncthreads();
        }
        if (t < nb) partials[t] = (t == 0) ? 0 : s[t - 1];
    } else if (t == 0) {
        int run = 0;
        for (int i = 0; i < nb; ++i) { int d = partials[i]; partials[i] = run; run += d; }
    }
}

// also zeroes the per-layer BN-stats accumulators (sums[0:nsum))
__global__ __launch_bounds__(256) void scan_add_kernel(int* __restrict__ rowptr,
                                                       int* __restrict__ cursor,
                                                       const int* __restrict__ partials,
                                                       float* __restrict__ sums, int nsum,
                                                       int N, int E) {
    int i = blockIdx.x * 256 + threadIdx.x;
    if (i < nsum) sums[i] = 0.f;
    if (i < N) {
        int v = rowptr[i] + partials[i >> 10];
        rowptr[i] = v;
        cursor[i] = v;
    }
    if (i == N) rowptr[N] = E;
}

// Scatter (edge id, src id) pairs into dst-ordered buckets
__global__ __launch_bounds__(256) void fill_kernel(const int* __restrict__ src,
                                                   const int* __restrict__ dst,
                                                   int* __restrict__ cursor,
                                                   int2* __restrict__ pbuf, int E) {
    int e = blockIdx.x * 256 + threadIdx.x;
    if (e >= E) return;
    int d = dst[e];
    int pos = atomicAdd(&cursor[d], 1);
    pbuf[pos] = make_int2(e, src[e]);
}

// Cast x (fp32, N*128) -> x16 (fp16), sequential
__global__ __launch_bounds__(256) void castx_kernel(const float* __restrict__ x,
                                                    _Float16* __restrict__ x16, int nq) {
    int i = blockIdx.x * 256 + threadIdx.x;
    if (i >= nq) return;
    f4 v = ((const f4*)x)[i];
    ((h4*)x16)[i] = __builtin_convertvector(v, h4);
}

// ---------------------------------------------------------------------------
// Gather-reduce: buf[n] = x16[n] + sum_{e in bucket(n)} relu(x16[src_e] + ea_e)
// One node per 32-lane group. 4-edge unroll. x side reads fp16 (halved random
// traffic, working set 12.8 MB). Accumulation fp32.
// MODE 0: read ea[e] fp32 (the ONE mandatory random pass over ea, NT) and
//         write eah[slot] fp16 — stores are SEQUENTIAL (slot order = bucket
//         order = this loop's iteration order).
// MODE 1: read eah[slot] fp16 sequentially (L3-resident, 128 MB).
// MODE 2: read ea fp32 random, no copy (single-layer case).
// ---------------------------------------------------------------------------
template <int MODE>
__global__ __launch_bounds__(256) void gather_kernel(const _Float16* __restrict__ x16,
                                                     const float* __restrict__ ea,
                                                     _Float16* __restrict__ eah,
                                                     const int* __restrict__ rowptr,
                                                     const int2* __restrict__ pbuf,
                                                     float* __restrict__ aggx, int N) {
    int t = blockIdx.x * 256 + threadIdx.x;
    int n = t >> 5;
    if (n >= N) return;
    int f = t & 31;
    int lo = rowptr[n], hi = rowptr[n + 1];
    const h4* xp = (const h4*)x16;
    f4 acc0 = __builtin_convertvector(xp[(size_t)n * 32 + f], f4);  // self (eps=0)
    f4 acc1 = {0.f, 0.f, 0.f, 0.f};
    f4 acc2 = {0.f, 0.f, 0.f, 0.f};
    f4 acc3 = {0.f, 0.f, 0.f, 0.f};
    int i = lo;
    if (MODE == 1) {
        const h4* ep = (const h4*)eah;
        for (; i + 4 <= hi; i += 4) {
            int2 q0 = pbuf[i];
            int2 q1 = pbuf[i + 1];
            int2 q2 = pbuf[i + 2];
            int2 q3 = pbuf[i + 3];
            h4 xa = xp[(size_t)q0.y * 32 + f];
            h4 ha = ep[(size_t)i * 32 + f];
            h4 xb = xp[(size_t)q1.y * 32 + f];
            h4 hb = ep[(size_t)(i + 1) * 32 + f];
            h4 xc = xp[(size_t)q2.y * 32 + f];
            h4 hc = ep[(size_t)(i + 2) * 32 + f];
            h4 xd = xp[(size_t)q3.y * 32 + f];
            h4 hd = ep[(size_t)(i + 3) * 32 + f];
            acc0 += relu4(__builtin_convertvector(xa, f4) + __builtin_convertvector(ha, f4));
            acc1 += relu4(__builtin_convertvector(xb, f4) + __builtin_convertvector(hb, f4));
            acc2 += relu4(__builtin_convertvector(xc, f4) + __builtin_convertvector(hc, f4));
            acc3 += relu4(__builtin_convertvector(xd, f4) + __builtin_convertvector(hd, f4));
        }
        for (; i < hi; ++i) {
            int2 q0 = pbuf[i];
            h4 xa = xp[(size_t)q0.y * 32 + f];
            h4 ha = ep[(size_t)i * 32 + f];
            acc0 += relu4(__builtin_convertvector(xa, f4) + __builtin_convertvector(ha, f4));
        }
    } else {
        h4* ep = (h4*)eah;
        for (; i + 4 <= hi; i += 4) {
            int2 q0 = pbuf[i];
            int2 q1 = pbuf[i + 1];
            int2 q2 = pbuf[i + 2];
            int2 q3 = pbuf[i + 3];
            h4 xa = xp[(size_t)q0.y * 32 + f];
            f4 aa = __builtin_nontemporal_load(((const f4*)(ea + (size_t)q0.x * 128)) + f);
            h4 xb = xp[(size_t)q1.y * 32 + f];
            f4 ab = __builtin_nontemporal_load(((const f4*)(ea + (size_t)q1.x * 128)) + f);
            h4 xc = xp[(size_t)q2.y * 32 + f];
            f4 ac = __builtin_nontemporal_load(((const f4*)(ea + (size_t)q2.x * 128)) + f);
            h4 xd = xp[(size_t)q3.y * 32 + f];
            f4 ad = __builtin_nontemporal_load(((const f4*)(ea + (size_t)q3.x * 128)) + f);
            if (MODE == 0) {
                ep[(size_t)i * 32 + f] = __builtin_convertvector(aa, h4);        // sequential
                ep[(size_t)(i + 1) * 32 + f] = __builtin_convertvector(ab, h4);
                ep[(size_t)(i + 2) * 32 + f] = __builtin_convertvector(ac, h4);
                ep[(size_t)(i + 3) * 32 + f] = __builtin_convertvector(ad, h4);
            }
            acc0 += relu4(__builtin_convertvector(xa, f4) + aa);
            acc1 += relu4(__builtin_convertvector(xb, f4) + ab);
            acc2 += relu4(__builtin_convertvector(xc, f4) + ac);
            acc3 += relu4(__builtin_convertvector(xd, f4) + ad);
        }
        for (; i < hi; ++i) {
            int2 q0 = pbuf[i];
            h4 xa = xp[(size_t)q0.y * 32 + f];
            f4 aa = __builtin_nontemporal_load(((const f4*)(ea + (size_t)q0.x * 128)) + f);
            if (MODE == 0) ep[(size_t)i * 32 + f] = __builtin_convertvector(aa, h4);
            acc0 += relu4(__builtin_convertvector(xa, f4) + aa);
        }
    }
    f4 r = (acc0 + acc1) + (acc2 + acc3);
    ((f4*)(aggx + (size_t)n * 128))[f] = r;
}

// ---------------------------------------------------------------------------
// GEMM1 (IN-PLACE capable: out may equal A): h = A @ W1 + b1,
// fused column sum/sumsq -> sums (1 atomic/col/block).
// ---------------------------------------------------------------------------
__global__ __launch_bounds__(256) void gemm1_kernel(const float* A,
                                                    const float* __restrict__ W,
                                                    const float* __restrict__ bias,
                                                    float* __restrict__ sums,
                                                    float* out, int N) {
    __shared__ float sA[64][132];
    __shared__ float sW[32][128];
    int t = threadIdx.x;
    int rbase = blockIdx.x * 64;

    {
        int colq = t & 31;
        int r0 = t >> 5;
#pragma unroll
        for (int it = 0; it < 8; ++it) {
            int r = r0 + it * 8;
            int row = rbase + r;
            float4 v = make_float4(0.f, 0.f, 0.f, 0.f);
            if (row < N) v = reinterpret_cast<const float4*>(A + (size_t)row * 128)[colq];
            *reinterpret_cast<float4*>(&sA[r][colq * 4]) = v;
        }
    }

    float acc[4][8];
#pragma unroll
    for (int r = 0; r < 4; ++r)
#pragma unroll
        for (int c = 0; c < 8; ++c) acc[r][c] = 0.f;

    int cg = t & 15, rg = t >> 4;
    int c0a = cg * 4;
    int c0b = 64 + cg * 4;

    for (int kc = 0; kc < 4; ++kc) {
        __syncthreads();
#pragma unroll
        for (int pass = 0; pass < 4; ++pass) {
            int kk = (t >> 5) + pass * 8;
            int k = kc * 32 + kk;
            float4 w = reinterpret_cast<const float4*>(W + (size_t)k * 128)[t & 31];
            *reinterpret_cast<float4*>(&sW[kk][(t & 31) * 4]) = w;
        }
        __syncthreads();
#pragma unroll
        for (int kk0 = 0; kk0 < 32; kk0 += 4) {
            float4 a[4];
#pragma unroll
            for (int r = 0; r < 4; ++r)
                a[r] = *reinterpret_cast<const float4*>(&sA[rg * 4 + r][kc * 32 + kk0]);
#pragma unroll
            for (int j = 0; j < 4; ++j) {
                float4 w0 = *reinterpret_cast<const float4*>(&sW[kk0 + j][c0a]);
                float4 w1 = *reinterpret_cast<const float4*>(&sW[kk0 + j][c0b]);
#pragma unroll
                for (int r = 0; r < 4; ++r) {
                    float av = (j == 0) ? a[r].x : (j == 1) ? a[r].y : (j == 2) ? a[r].z : a[r].w;
                    acc[r][0] += av * w0.x;
                    acc[r][1] += av * w0.y;
                    acc[r][2] += av * w0.z;
                    acc[r][3] += av * w0.w;
                    acc[r][4] += av * w1.x;
                    acc[r][5] += av * w1.y;
                    acc[r][6] += av * w1.z;
                    acc[r][7] += av * w1.w;
                }
            }
        }
    }

    float4 b0 = *reinterpret_cast<const float4*>(bias + c0a);
    float4 b1v = *reinterpret_cast<const float4*>(bias + c0b);
    float cs[8], cs2[8];
#pragma unroll
    for (int j = 0; j < 8; ++j) { cs[j] = 0.f; cs2[j] = 0.f; }

#pragma unroll
    for (int r = 0; r < 4; ++r) {
        int row = rbase + rg * 4 + r;
        if (row >= N) continue;
        float4 o0, o1;
        o0.x = acc[r][0] + b0.x;  o0.y = acc[r][1] + b0.y;
        o0.z = acc[r][2] + b0.z;  o0.w = acc[r][3] + b0.w;
        o1.x = acc[r][4] + b1v.x; o1.y = acc[r][5] + b1v.y;
        o1.z = acc[r][6] + b1v.z; o1.w = acc[r][7] + b1v.w;
        cs[0] += o0.x; cs2[0] += o0.x * o0.x;
        cs[1] += o0.y; cs2[1] += o0.y * o0.y;
        cs[2] += o0.z; cs2[2] += o0.z * o0.z;
        cs[3] += o0.w; cs2[3] += o0.w * o0.w;
        cs[4] += o1.x; cs2[4] += o1.x * o1.x;
        cs[5] += o1.y; cs2[5] += o1.y * o1.y;
        cs[6] += o1.z; cs2[6] += o1.z * o1.z;
        cs[7] += o1.w; cs2[7] += o1.w * o1.w;
        *reinterpret_cast<float4*>(out + (size_t)row * 128 + c0a) = o0;
        *reinterpret_cast<float4*>(out + (size_t)row * 128 + c0b) = o1;
    }

    __syncthreads();
    float* red = &sA[0][0];
    float* red2 = red + 2048;
    int base = (rg * 16 + cg) * 8;
#pragma unroll
    for (int j = 0; j < 8; ++j) { red[base + j] = cs[j]; red2[base + j] = cs2[j]; }
    __syncthreads();
    if (t < 128) {
        int cgj = (t & 63) >> 2;
        int j = (t & 3) + ((t >> 6) << 2);
        float s = 0.f, s2 = 0.f;
#pragma unroll
        for (int rr = 0; rr < 16; ++rr) {
            s += red[(rr * 16 + cgj) * 8 + j];
            s2 += red2[(rr * 16 + cgj) * 8 + j];
        }
        unsafeAtomicAdd(&sums[t], s);
        unsafeAtomicAdd(&sums[128 + t], s2);
    }
}

// ---------------------------------------------------------------------------
// GEMM2: y = relu( relu(h*scale + shift) @ W2 + b2 )
// WX16=1: write y as fp16 into x16 (layer boundary; x16 region is dead by now)
// WX16=0: write y as fp32 into out (final layer; overwrites x16 region last)
// ---------------------------------------------------------------------------
template <int WX16>
__global__ __launch_bounds__(256) void gemm2_kernel(const float* __restrict__ A,
                                                    const float* __restrict__ W,
                                                    const float* __restrict__ bias,
                                                    const float* __restrict__ sums,
                                                    const float* __restrict__ gamma,
                                                    const float* __restrict__ beta,
                                                    float* __restrict__ out,
                                                    _Float16* __restrict__ x16, int N,
                                                    float invN) {
    __shared__ float sA[64][132];
    __shared__ float sW[32][128];
    __shared__ float sScale[128];
    __shared__ float sShift[128];
    int t = threadIdx.x;
    int rbase = blockIdx.x * 64;

    if (t < 128) {
        float mean = sums[t] * invN;
        float var = sums[128 + t] * invN - mean * mean;
        float inv = rsqrtf(var + BN_EPS);
        float sc = gamma[t] * inv;
        sScale[t] = sc;
        sShift[t] = beta[t] - mean * sc;
    }
    __syncthreads();

    {
        int colq = t & 31;
        int r0 = t >> 5;
        float4 s4 = reinterpret_cast<const float4*>(sScale)[colq];
        float4 sh4 = reinterpret_cast<const float4*>(sShift)[colq];
#pragma unroll
        for (int it = 0; it < 8; ++it) {
            int r = r0 + it * 8;
            int row = rbase + r;
            float4 v = make_float4(0.f, 0.f, 0.f, 0.f);
            if (row < N) {
                float4 a = reinterpret_cast<const float4*>(A + (size_t)row * 128)[colq];
                v.x = fmaxf(a.x * s4.x + sh4.x, 0.f);
                v.y = fmaxf(a.y * s4.y + sh4.y, 0.f);
                v.z = fmaxf(a.z * s4.z + sh4.z, 0.f);
                v.w = fmaxf(a.w * s4.w + sh4.w, 0.f);
            }
            *reinterpret_cast<float4*>(&sA[r][colq * 4]) = v;
        }
    }

    float acc[4][8];
#pragma unroll
    for (int r = 0; r < 4; ++r)
#pragma unroll
        for (int c = 0; c < 8; ++c) acc[r][c] = 0.f;

    int cg = t & 15, rg = t >> 4;
    int c0a = cg * 4;
    int c0b = 64 + cg * 4;

    for (int kc = 0; kc < 4; ++kc) {
        __syncthreads();
#pragma unroll
        for (int pass = 0; pass < 4; ++pass) {
            int kk = (t >> 5) + pass * 8;
            int k = kc * 32 + kk;
            float4 w = reinterpret_cast<const float4*>(W + (size_t)k * 128)[t & 31];
            *reinterpret_cast<float4*>(&sW[kk][(t & 31) * 4]) = w;
        }
        __syncthreads();
#pragma unroll
        for (int kk0 = 0; kk0 < 32; kk0 += 4) {
            float4 a[4];
#pragma unroll
            for (int r = 0; r < 4; ++r)
                a[r] = *reinterpret_cast<const float4*>(&sA[rg * 4 + r][kc * 32 + kk0]);
#pragma unroll
            for (int j = 0; j < 4; ++j) {
                float4 w0 = *reinterpret_cast<const float4*>(&sW[kk0 + j][c0a]);
                float4 w1 = *reinterpret_cast<const float4*>(&sW[kk0 + j][c0b]);
#pragma unroll
                for (int r = 0; r < 4; ++r) {
                    float av = (j == 0) ? a[r].x : (j == 1) ? a[r].y : (j == 2) ? a[r].z : a[r].w;
                    acc[r][0] += av * w0.x;
                    acc[r][1] += av * w0.y;
                    acc[r][2] += av * w0.z;
                    acc[r][3] += av * w0.w;
                    acc[r][4] += av * w1.x;
                    acc[r][5] += av * w1.y;
                    acc[r][6] += av * w1.z;
                    acc[r][7] += av * w1.w;
                }
            }
        }
    }

    float4 b0 = *reinterpret_cast<const float4*>(bias + c0a);
    float4 b1v = *reinterpret_cast<const float4*>(bias + c0b);
#pragma unroll
    for (int r = 0; r < 4; ++r) {
        int row = rbase + rg * 4 + r;
        if (row >= N) continue;
        f4 o0, o1;
        o0.x = fmaxf(acc[r][0] + b0.x, 0.f);  o0.y = fmaxf(acc[r][1] + b0.y, 0.f);
        o0.z = fmaxf(acc[r][2] + b0.z, 0.f);  o0.w = fmaxf(acc[r][3] + b0.w, 0.f);
        o1.x = fmaxf(acc[r][4] + b1v.x, 0.f); o1.y = fmaxf(acc[r][5] + b1v.y, 0.f);
        o1.z = fmaxf(acc[r][6] + b1v.z, 0.f); o1.w = fmaxf(acc[r][7] + b1v.w, 0.f);
        if (WX16) {
            h4* xp = (h4*)(x16 + (size_t)row * 128);
            xp[cg] = __builtin_convertvector(o0, h4);
            xp[16 + cg] = __builtin_convertvector(o1, h4);
        } else {
            *reinterpret_cast<f4*>(out + (size_t)row * 128 + c0a) = o0;
            *reinterpret_cast<f4*>(out + (size_t)row * 128 + c0b) = o1;
        }
    }
}

// ---------------------------------------------------------------------------
extern "C" void kernel_launch(void* const* d_in, const int* in_sizes, int n_in,
                              void* d_out, int out_size, void* d_ws, size_t ws_size,
                              hipStream_t stream) {
    const float* x     = (const float*)d_in[0];
    const int*   ei    = (const int*)d_in[1];
    const float* ea    = (const float*)d_in[2];
    const float* W1    = (const float*)d_in[3];
    const float* b1    = (const float*)d_in[4];
    const float* gamma = (const float*)d_in[5];
    const float* beta  = (const float*)d_in[6];
    const float* W2    = (const float*)d_in[7];
    const float* b2    = (const float*)d_in[8];

    int N = in_sizes[0] / 128;
    int E = in_sizes[2] / 128;
    int L = in_sizes[3] / (128 * 128);

    // Workspace layout: byte-identical to the proven R8 map (no x16 here).
    size_t NF = (size_t)N * 128;
    float*     buf    = (float*)d_ws;                  // gather out + gemm1 in-place
    float*     sums   = buf + NF;                      // 256*L floats
    _Float16*  eah    = (_Float16*)(sums + 256 * L);   // E*128 halves (bucket order)
    int*       canon  = (int*)(eah + (size_t)E * 128);
    int*       deg    = canon + (size_t)2 * E;
    int*       rowptr = deg + N;
    int*       cursor = rowptr + N + 2;                // pad keeps pbuf 8B-aligned
    int2*      pbuf   = (int2*)(cursor + N);           // (edge id, src id), bucket order
    int*       partials = (int*)(pbuf + E);
    int*       flag   = partials + ((N + 1023) / 1024) + 1;

    // x16 lives in d_out (25.6 MB fp32 scratch until the final fp32 write;
    // fp16 x16 needs only the first half). Lifetime: castx -> gather(l) reads,
    // gemm2<1> overwrites with next layer's x; final gemm2<0> overwrites all.
    _Float16* x16 = (_Float16*)d_out;

    // ---- Canonicalize edges + degree histogram ----
    int npairs = (E < 4096) ? E : 4096;
    detect_i64_kernel<<<1, 256, 0, stream>>>(ei, flag, npairs, deg, N);
    int E2 = 2 * E;
    canon_kernel<<<(E2 + 255) / 256, 256, 0, stream>>>(ei, flag, canon, deg, E2, E);
    const int* src = canon;
    const int* dst = canon + E;

    // ---- Parallel scan + CSR fill + x cast (once) ----
    int nb = (N + 1023) / 1024;
    scan_blk_kernel<<<nb, 256, 0, stream>>>(deg, rowptr, partials, N);
    scan_part_kernel<<<1, 256, 0, stream>>>(partials, nb);
    scan_add_kernel<<<(N + 256) / 256, 256, 0, stream>>>(rowptr, cursor, partials,
                                                         sums, 256 * L, N, E);
    int eBlocks = (E + 255) / 256;
    fill_kernel<<<eBlocks, 256, 0, stream>>>(src, dst, cursor, pbuf, E);
    int nq = (int)(NF >> 2);
    castx_kernel<<<(nq + 255) / 256, 256, 0, stream>>>(x, x16, nq);

    // ---- Layers ----
    int gatherBlocks = (N * 32 + 255) / 256;
    int gemmBlocks = (N + 63) / 64;
    float invN = 1.0f / (float)N;
    for (int l = 0; l < L; ++l) {
        float* sums_l = sums + (size_t)l * 256;
        if (l == 0) {
            if (L > 1)
                gather_kernel<0><<<gatherBlocks, 256, 0, stream>>>(x16, ea, eah, rowptr,
                                                                   pbuf, buf, N);
            else
                gather_kernel<2><<<gatherBlocks, 256, 0, stream>>>(x16, ea, eah, rowptr,
                                                                   pbuf, buf, N);
        } else {
            gather_kernel<1><<<gatherBlocks, 256, 0, stream>>>(x16, ea, eah, rowptr,
                                                               pbuf, buf, N);
        }
        gemm1_kernel<<<gemmBlocks, 256, 0, stream>>>(buf, W1 + (size_t)l * 16384,
                                                     b1 + (size_t)l * 128, sums_l, buf, N);
        if (l < L - 1)
            gemm2_kernel<1><<<gemmBlocks, 256, 0, stream>>>(buf, W2 + (size_t)l * 16384,
                                                            b2 + (size_t)l * 128, sums_l,
                                                            gamma + (size_t)l * 128,
                                                            beta + (size_t)l * 128,
                                                            (float*)d_out, x16, N, invN);
        else
            gemm2_kernel<0><<<gemmBlocks, 256, 0, stream>>>(buf, W2 + (size_t)l * 16384,
                                                            b2 + (size_t)l * 128, sums_l,
                                                            gamma + (size_t)l * 128,
                                                            beta + (size_t)l * 128,
                                                            (float*)d_out, x16, N, invN);
    }
}